// Round 3
// baseline (125.572 us; speedup 1.0000x reference)
//
#include <hip/hip_runtime.h>
#include <hip/hip_bf16.h>

// HybridSurvivalQ: quantum expval collapses to prod_{q=1..6} cos(x_q[q]+p[q])
// (CNOT ring => final bit0 = parity of bits 1..6; per-qubit E = cos(x+p)).
// Then MLP 65->32->16->1 with ReLU. fp32 vector ALU.
//
// R1: dur_us dominated by harness reset fills (268MB, 42-45us x2 per iter);
//     kernel itself ~17us, invisible in top-5.
// R2: NO runtime-indexed per-thread arrays (scratch spill + replay divergence).
// R3 REGRESSION (113.6): full unroll + all loads upfront. Reverted.
// R4 NEUTRAL (105.1): 1-deep pipeline on rolled loop. Kernel still ~17us ->
//     ILP is not the binding constraint; occupancy is (2 waves/SIMD).
// R5 change: 2 threads per row in DIFFERENT waves of the same block.
//     half0 wave: qv + features 0..31; half1 wave: features 32..63.
//     half stays wave-uniform -> W1 pointer uniform -> s_load batches kept
//     (the thing that made R3-style lane-splits lose). Partials combined via
//     padded LDS [128][33] (bank = (lane+j)%32, 2-way = free) + one barrier.
//     4 waves/SIMD, per-thread layer-1 chain halved.

#define NQ 7
#define F  64
#define H1 32
#define H2 16
#define RPB 128   // rows per 256-thread block (2 threads/row)

// 128-FMA layer-1 sub-block: acc1 += outer(xv, W[4 rows])
#define L1_BODY(XV, WPTR)                                                    \
    do {                                                                     \
        const float* w_ = (WPTR);                                            \
        _Pragma("unroll")                                                    \
        for (int j = 0; j < H1; ++j) acc1[j] = fmaf((XV).x, w_[j],          acc1[j]); \
        _Pragma("unroll")                                                    \
        for (int j = 0; j < H1; ++j) acc1[j] = fmaf((XV).y, w_[H1 + j],     acc1[j]); \
        _Pragma("unroll")                                                    \
        for (int j = 0; j < H1; ++j) acc1[j] = fmaf((XV).z, w_[2 * H1 + j], acc1[j]); \
        _Pragma("unroll")                                                    \
        for (int j = 0; j < H1; ++j) acc1[j] = fmaf((XV).w, w_[3 * H1 + j], acc1[j]); \
    } while (0)

__global__ __launch_bounds__(256) void hybrid_fused(
    const float* __restrict__ x_q, const float* __restrict__ x_c,
    const float* __restrict__ q_params,
    const float* __restrict__ W1, const float* __restrict__ b1,
    const float* __restrict__ W2, const float* __restrict__ b2,
    const float* __restrict__ W3, const float* __restrict__ b3,
    float* __restrict__ out, int B)
{
    __shared__ float part[RPB][H1 + 1];   // +1 pad: conflict-free column writes

    const int tid  = threadIdx.x;
    const int wid  = tid >> 6;            // wave 0..3
    const int lane = tid & 63;
    const int half = wid & 1;             // wave-uniform half selector
    const int lrow = (wid >> 1) * 64 + lane;              // 0..127
    const int row  = blockIdx.x * RPB + lrow;
    const bool active = (row < B);

    float acc1[H1];

    if (active) {
        // ---- layer-1 partial over this half's 32 features ----
        if (half == 0) {
            // quantum expectation (closed form) + k=0 row + bias
            float qv = 1.0f;
            #pragma unroll
            for (int q = 1; q < NQ; ++q)
                qv *= __cosf(x_q[(size_t)row * NQ + q] + q_params[q]);
            #pragma unroll
            for (int j = 0; j < H1; ++j)
                acc1[j] = fmaf(qv, W1[j], b1[j]);
        } else {
            #pragma unroll
            for (int j = 0; j < H1; ++j) acc1[j] = 0.0f;
        }

        const float4* xc4 = reinterpret_cast<const float4*>(
            x_c + (size_t)row * F + half * (F / 2));
        const float* wbase = W1 + (size_t)(1 + half * (F / 2)) * H1;  // uniform

        // rolled + 1-deep pipeline, 8 iterations of 128 FMA
        float4 cur = xc4[0];
        #pragma unroll 1
        for (int k4 = 0; k4 < F / 8 - 1; ++k4) {
            const float4 nxt = xc4[k4 + 1];
            L1_BODY(cur, wbase + (size_t)(4 * k4) * H1);
            cur = nxt;
        }
        L1_BODY(cur, wbase + (size_t)(4 * (F / 8 - 1)) * H1);

        if (half == 1) {
            #pragma unroll
            for (int j = 0; j < H1; ++j) part[lrow][j] = acc1[j];
        }
    }

    __syncthreads();   // unconditional: all 256 threads reach it

    if (half == 1 || !active) return;

    // ---- combine halves ----
    #pragma unroll
    for (int j = 0; j < H1; ++j) acc1[j] += part[lrow][j];

    // ---- layer 2: relu(acc1)(32) @ W2(32x16) + b2 (fully unrolled) ----
    float acc2[H2];
    #pragma unroll
    for (int j = 0; j < H2; ++j) acc2[j] = b2[j];
    #pragma unroll
    for (int k = 0; k < H1; ++k) {
        const float h = fmaxf(acc1[k], 0.0f);
        #pragma unroll
        for (int j = 0; j < H2; ++j)
            acc2[j] = fmaf(h, W2[k * H2 + j], acc2[j]);
    }

    // ---- layer 3: relu(acc2)(16) @ W3(16x1) + b3 ----
    float o = b3[0];
    #pragma unroll
    for (int k = 0; k < H2; ++k)
        o = fmaf(fmaxf(acc2[k], 0.0f), W3[k], o);

    out[row] = o;
}

extern "C" void kernel_launch(void* const* d_in, const int* in_sizes, int n_in,
                              void* d_out, int out_size, void* d_ws, size_t ws_size,
                              hipStream_t stream) {
    const float* x_q      = (const float*)d_in[0];
    const float* x_c      = (const float*)d_in[1];
    const float* q_params = (const float*)d_in[2];
    const float* W1       = (const float*)d_in[3];
    const float* b1       = (const float*)d_in[4];
    const float* W2       = (const float*)d_in[5];
    const float* b2       = (const float*)d_in[6];
    const float* W3       = (const float*)d_in[7];
    const float* b3       = (const float*)d_in[8];
    float* out = (float*)d_out;

    const int B = in_sizes[0] / NQ;        // 131072
    const int grid = (B + RPB - 1) / RPB;  // 1024 blocks of 256 (2 thr/row)

    hybrid_fused<<<grid, 256, 0, stream>>>(x_q, x_c, q_params,
                                           W1, b1, W2, b2, W3, b3,
                                           out, B);
}

// Round 4
// 104.992 us; speedup vs baseline: 1.1960x; 1.1960x over previous
//
#include <hip/hip_runtime.h>
#include <hip/hip_bf16.h>

// HybridSurvivalQ: quantum expval collapses to prod_{q=1..6} cos(x_q[q]+p[q])
// (CNOT ring => final bit0 = parity of bits 1..6; per-qubit E = cos(x+p)).
// Then MLP 65->32->16->1 with ReLU. fp32 vector ALU.
//
// R1: dur_us includes ~87us of harness reset fills (268MB poisons, 2/iter).
// R2: NO runtime-indexed per-thread arrays (scratch spill + replay divergence).
// R3 REGRESSION (113.6): full unroll + 22 upfront strided loads.
// R4 NEUTRAL (105.1): 1-deep pipeline on rolled loop; kernel ~17us.
// R5 REGRESSION (125.6): 2-thread/row split; kernel MEASURED 44.7us with
//    VALUBusy 12.9%, HBM 5.4% -> LATENCY-bound, not BW/VALU. More TLP over
//    the same strided pattern didn't help.
// R6 diagnosis: thread-per-row + row-major x_c => lane i loads at 256B
//    stride: each wave load touches 64 cache lines at 16/64B utilization ->
//    4x request amplification, TA/TCP serialization, exposed vmcnt latency
//    every iteration. FIX: coalesced cooperative staging of the block's
//    [256x64] x_c tile into LDS (consecutive lanes -> consecutive 16B, every
//    line fully consumed, 16 independent loads/thread), then the PROVEN R4
//    compute loop reads its row from LDS (ds_read_b128, row stride padded to
//    68 floats -> bank group = row*17+k, odd stride -> 2-way aliasing = free).
//    x_q staged too (kills stride-28 scalar loads). LDS 76.8KB = 2 blocks/CU.

#define NQ 7
#define F  64
#define H1 32
#define H2 16
#define RPB 256          // rows per block == threads per block
#define LDW (F + 4)      // padded LDS row stride (68 floats, 16B-aligned)

// 128-FMA layer-1 sub-block: acc1 += outer(xv, W[4 rows])
#define L1_BODY(XV, WPTR)                                                    \
    do {                                                                     \
        const float* w_ = (WPTR);                                            \
        _Pragma("unroll")                                                    \
        for (int j = 0; j < H1; ++j) acc1[j] = fmaf((XV).x, w_[j],          acc1[j]); \
        _Pragma("unroll")                                                    \
        for (int j = 0; j < H1; ++j) acc1[j] = fmaf((XV).y, w_[H1 + j],     acc1[j]); \
        _Pragma("unroll")                                                    \
        for (int j = 0; j < H1; ++j) acc1[j] = fmaf((XV).z, w_[2 * H1 + j], acc1[j]); \
        _Pragma("unroll")                                                    \
        for (int j = 0; j < H1; ++j) acc1[j] = fmaf((XV).w, w_[3 * H1 + j], acc1[j]); \
    } while (0)

__global__ __launch_bounds__(256) void hybrid_fused(
    const float* __restrict__ x_q, const float* __restrict__ x_c,
    const float* __restrict__ q_params,
    const float* __restrict__ W1, const float* __restrict__ b1,
    const float* __restrict__ W2, const float* __restrict__ b2,
    const float* __restrict__ W3, const float* __restrict__ b3,
    float* __restrict__ out, int B)
{
    __shared__ float tile[RPB][LDW];     // 69,632 B
    __shared__ float xqs[RPB * NQ];      //  7,168 B  (total 76.8KB -> 2 blk/CU)

    const int tid = threadIdx.x;
    const size_t blk_row0 = (size_t)blockIdx.x * RPB;
    // B = 131072 = 512 * RPB exactly; grid is exact, no partial blocks.

    // ---- phase 1: coalesced staging ----
    // x_c tile: 256 rows x 16 float4 = 4096 float4s; lane-consecutive =
    // address-consecutive; every 64B line fully consumed.
    const float4* src = reinterpret_cast<const float4*>(x_c + blk_row0 * F);
    #pragma unroll
    for (int i = 0; i < 16; ++i) {
        const int fidx = i * 256 + tid;          // 0..4095
        const int r    = fidx >> 4;              // row 0..255
        const int k    = fidx & 15;              // float4 index 0..15
        *reinterpret_cast<float4*>(&tile[r][k * 4]) = src[fidx];
        // ds_write bank group = r*17 + k: <=2-way aliasing per wave (free)
    }
    // x_q: 1792 consecutive floats
    const float* qsrc = x_q + blk_row0 * NQ;
    #pragma unroll
    for (int i = 0; i < NQ; ++i)
        xqs[i * 256 + tid] = qsrc[i * 256 + tid];

    __syncthreads();

    // ---- phase 2: proven R4 compute loop, fed from LDS ----
    // quantum expectation (closed form); xqs[tid*7+q]: stride 7 (odd) ->
    // distinct banks mod 32, 2-way over the wave = free.
    float qv = 1.0f;
    #pragma unroll
    for (int q = 1; q < NQ; ++q)
        qv *= __cosf(xqs[tid * NQ + q] + q_params[q]);

    // layer 1: combined(65) @ W1(65x32) + b1; combined[0]=qv
    float acc1[H1];
    #pragma unroll
    for (int j = 0; j < H1; ++j)
        acc1[j] = fmaf(qv, W1[j], b1[j]);       // k=0 row of W1

    const float4* rowlds = reinterpret_cast<const float4*>(&tile[tid][0]);
    #pragma unroll 1   // rolled: compact 1KB hot loop, compiler-pipelined
    for (int k4 = 0; k4 < F / 4; ++k4) {
        const float4 xv = rowlds[k4];           // ds_read_b128, 2-way = free
        L1_BODY(xv, W1 + (size_t)(1 + 4 * k4) * H1);  // wave-uniform s_load
    }

    // layer 2: relu(acc1)(32) @ W2(32x16) + b2 (fully unrolled, registers)
    float acc2[H2];
    #pragma unroll
    for (int j = 0; j < H2; ++j) acc2[j] = b2[j];
    #pragma unroll
    for (int k = 0; k < H1; ++k) {
        const float h = fmaxf(acc1[k], 0.0f);
        #pragma unroll
        for (int j = 0; j < H2; ++j)
            acc2[j] = fmaf(h, W2[k * H2 + j], acc2[j]);
    }

    // layer 3: relu(acc2)(16) @ W3(16x1) + b3
    float o = b3[0];
    #pragma unroll
    for (int k = 0; k < H2; ++k)
        o = fmaf(fmaxf(acc2[k], 0.0f), W3[k], o);

    out[blk_row0 + tid] = o;                    // coalesced store
}

extern "C" void kernel_launch(void* const* d_in, const int* in_sizes, int n_in,
                              void* d_out, int out_size, void* d_ws, size_t ws_size,
                              hipStream_t stream) {
    const float* x_q      = (const float*)d_in[0];
    const float* x_c      = (const float*)d_in[1];
    const float* q_params = (const float*)d_in[2];
    const float* W1       = (const float*)d_in[3];
    const float* b1       = (const float*)d_in[4];
    const float* W2       = (const float*)d_in[5];
    const float* b2       = (const float*)d_in[6];
    const float* W3       = (const float*)d_in[7];
    const float* b3       = (const float*)d_in[8];
    float* out = (float*)d_out;

    const int B = in_sizes[0] / NQ;        // 131072
    const int grid = (B + RPB - 1) / RPB;  // 512 blocks of 256, exact

    hybrid_fused<<<grid, 256, 0, stream>>>(x_q, x_c, q_params,
                                           W1, b1, W2, b2, W3, b3,
                                           out, B);
}